// Round 2
// baseline (90.360 us; speedup 1.0000x reference)
//
#include <hip/hip_runtime.h>

// out[b,n] = 1/(16*15^4) * sum_jf Acoeff[n,jf] * S[b,jf]
// S[b,jf]  = G[jf,:] . T[b,jf,:],   G = Bbasis @ M   (81x32)
// T[b,jf,m]= sum_{p,q,r,s} w[j1][p] w[j2][q] w[j3][r] w[j4][s] arr[b,p,q,r,s,m]
// per-dim coverage masks (D=16, L=3, R=2, VALID, stride 1):
//   class0: 0x36DB  class1: 0x6DB6  class2: 0xDB6C

static __device__ __forceinline__ void add4(float4& a, const float4& b) {
    a.x += b.x; a.y += b.y; a.z += b.z; a.w += b.w;
}
static __device__ __forceinline__ void fma4(float4& a, float w, const float4& b) {
    a.x = fmaf(w, b.x, a.x); a.y = fmaf(w, b.y, a.y);
    a.z = fmaf(w, b.z, a.z); a.w = fmaf(w, b.w, a.w);
}

// ---- prep: G = Bbasis @ M  (81x32), and zero d_out ----
__global__ __launch_bounds__(128) void sdd4_prep(
    const float* __restrict__ Mmat,    // [32,32]
    const float* __restrict__ Bbasis,  // [81,32]
    float* __restrict__ G,             // [81,32] (d_ws)
    float* __restrict__ out)           // [4,32]
{
    __shared__ float M_lds[32 * 33];   // [n][m] padded
    const int t  = threadIdx.x;
    const int bx = blockIdx.x;         // 0..3

    const float4* M4 = reinterpret_cast<const float4*>(Mmat);
    for (int i = t; i < 256; i += 128) {
        float4 v = M4[i];
        float* dst = &M_lds[(i >> 3) * 33 + (i & 7) * 4];
        dst[0] = v.x; dst[1] = v.y; dst[2] = v.z; dst[3] = v.w;
    }
    if (bx == 0 && t < 128) out[t] = 0.0f;
    __syncthreads();

    const int base = bx * 648;         // 2592 / 4
    for (int k = 0; k < 6; ++k) {
        const int o = base + t + k * 128;
        if (o < base + 648) {
            const int jf = o >> 5, m = o & 31;
            const float4* Br = reinterpret_cast<const float4*>(Bbasis + jf * 32);
            float acc = 0.f;
            #pragma unroll
            for (int nv = 0; nv < 8; ++nv) {
                float4 bv = Br[nv];
                acc = fmaf(bv.x, M_lds[(nv * 4 + 0) * 33 + m], acc);
                acc = fmaf(bv.y, M_lds[(nv * 4 + 1) * 33 + m], acc);
                acc = fmaf(bv.z, M_lds[(nv * 4 + 2) * 33 + m], acc);
                acc = fmaf(bv.w, M_lds[(nv * 4 + 3) * 33 + m], acc);
            }
            G[o] = acc;
        }
    }
}

// ---- main: one block per (b,p,q); HBM pass + tiny epilogue ----
__global__ __launch_bounds__(128) void sdd4_main(
    const float* __restrict__ arr,     // [4,16,16,16,16,32]
    const float* __restrict__ G,       // [81,32]
    const float* __restrict__ Acoeff,  // [32,81]
    float* __restrict__ out)           // [4,32]
{
    __shared__ float4 U_lds[400];      // [r*25 + class*8 + mv]
    __shared__ float  V_lds[9 * 33];   // [jj][m]
    __shared__ float  G_lds[81 * 33];  // [jf][m]
    __shared__ float  A_lds[81 * 33];  // [jf][n]  (Acoeff transposed)
    __shared__ float  c_lds[40];
    __shared__ int    jf_lds[40];

    const int t  = threadIdx.x;
    const int bx = blockIdx.x;         // 0..1023
    const int b  = bx >> 8;
    const int p  = (bx >> 4) & 15;
    const int q  = bx & 15;

    // stage G (coalesced float4) and Acoeff^T (coalesced b32) into LDS
    const float4* G4 = reinterpret_cast<const float4*>(G);
    for (int i = t; i < 648; i += 128) {
        float4 v = G4[i];
        float* dst = &G_lds[(i >> 3) * 33 + (i & 7) * 4];
        dst[0] = v.x; dst[1] = v.y; dst[2] = v.z; dst[3] = v.w;
    }
    if (t < 81) {
        #pragma unroll
        for (int n = 0; n < 32; ++n)
            A_lds[t * 33 + n] = Acoeff[n * 81 + t];
    }

    // main HBM pass: reduce over s per class
    const int r  = t >> 3;             // 0..15
    const int mv = t & 7;              // float4 idx in m
    const float4* A4 = reinterpret_cast<const float4*>(arr);
    const size_t tile = (size_t)((b * 16 + p) * 16 + q) * 2048;

    float4 u0 = make_float4(0.f, 0.f, 0.f, 0.f), u1 = u0, u2 = u0;
    #pragma unroll
    for (int s = 0; s < 16; ++s) {
        float4 x = A4[tile + (size_t)(r * 16 + s) * 8 + mv];
        if ((0x36DBu >> s) & 1) add4(u0, x);
        if ((0x6DB6u >> s) & 1) add4(u1, x);
        if ((0xDB6Cu >> s) & 1) add4(u2, x);
    }
    U_lds[r * 25 +      mv] = u0;
    U_lds[r * 25 +  8 + mv] = u1;
    U_lds[r * 25 + 16 + mv] = u2;
    __syncthreads();

    // reduce over r per class -> V[jj][m], jj = j3*3 + j4
    if (t < 72) {
        const int j3  = t / 24;
        const int rem = t % 24;
        const int j4  = rem >> 3;
        const int mv2 = rem & 7;
        const unsigned msk = (j3 == 0) ? 0x36DBu : (j3 == 1 ? 0x6DB6u : 0xDB6Cu);
        float4 acc = make_float4(0.f, 0.f, 0.f, 0.f);
        #pragma unroll
        for (int rr = 0; rr < 16; ++rr) {
            float w = (float)((msk >> rr) & 1u);
            fma4(acc, w, U_lds[rr * 25 + j4 * 8 + mv2]);
        }
        const int jj = j3 * 3 + j4;
        float* dv = &V_lds[jj * 33 + mv2 * 4];
        dv[0] = acc.x; dv[1] = acc.y; dv[2] = acc.z; dv[3] = acc.w;
    }
    __syncthreads();

    // combos for this (p,q): c_jf = G[jf,:] . V[jj,:]
    int l1_0, l1_1 = 0, n1;
    if      (p == 0)  { l1_0 = 0; n1 = 1; }
    else if (p == 15) { l1_0 = 2; n1 = 1; }
    else              { l1_0 = (p - 1) % 3; l1_1 = p % 3; n1 = 2; }
    int l2_0, l2_1 = 0, n2;
    if      (q == 0)  { l2_0 = 0; n2 = 1; }
    else if (q == 15) { l2_0 = 2; n2 = 1; }
    else              { l2_0 = (q - 1) % 3; l2_1 = q % 3; n2 = 2; }

    const int ncomb = n1 * n2 * 9;
    if (t < ncomb) {
        const int jj  = t % 9;
        const int c12 = t / 9;
        const int i1idx = (n2 == 2) ? (c12 >> 1) : c12;
        const int i2idx = (n2 == 2) ? (c12 & 1)  : 0;
        const int i1 = i1idx ? l1_1 : l1_0;
        const int i2 = i2idx ? l2_1 : l2_0;
        const int jf = (i1 * 3 + i2) * 9 + jj;
        float acc = 0.f;
        #pragma unroll
        for (int m = 0; m < 32; ++m)
            acc = fmaf(G_lds[jf * 33 + m], V_lds[jj * 33 + m], acc);
        c_lds[t]  = acc;
        jf_lds[t] = jf;
    }
    __syncthreads();

    // apply Acoeff, one atomic per (b,n) per block
    if (t < 32) {
        float acc = 0.f;
        for (int k = 0; k < ncomb; ++k)
            acc = fmaf(A_lds[jf_lds[k] * 33 + t], c_lds[k], acc);
        atomicAdd(&out[b * 32 + t], acc * (1.0f / 810000.0f));
    }
}

extern "C" void kernel_launch(void* const* d_in, const int* in_sizes, int n_in,
                              void* d_out, int out_size, void* d_ws, size_t ws_size,
                              hipStream_t stream) {
    const float* arr    = (const float*)d_in[0];  // [4,16,16,16,16,32]
    const float* Mmat   = (const float*)d_in[1];  // [32,32]
    const float* Acoeff = (const float*)d_in[2];  // [32,81]
    const float* Bbasis = (const float*)d_in[3];  // [81,32]
    float* G = (float*)d_ws;                      // 81*32 floats

    sdd4_prep<<<dim3(4),    dim3(128), 0, stream>>>(Mmat, Bbasis, G, (float*)d_out);
    sdd4_main<<<dim3(1024), dim3(128), 0, stream>>>(arr, G, Acoeff, (float*)d_out);
}

// Round 3
// 88.223 us; speedup vs baseline: 1.0242x; 1.0242x over previous
//
#include <hip/hip_runtime.h>

// out[b,n] = 1/(16*15^4) * sum_jf Acoeff[n,jf] * S[b,jf]
// S[b,jf]  = G[jf,:] . T[b,jf,:],   G = Bbasis @ M   (81x32)
// T[b,jf,m]= sum_{p,q,r,s} w[j1][p] w[j2][q] w[j3][r] w[j4][s] arr[b,p,q,r,s,m]
// per-dim coverage masks (D=16, L=3, R=2, VALID, stride 1):
//   class0: 0x36DB  class1: 0x6DB6  class2: 0xDB6C

static __device__ __forceinline__ void add4(float4& a, const float4& b) {
    a.x += b.x; a.y += b.y; a.z += b.z; a.w += b.w;
}

// ---- prep: G = Bbasis @ M  (81x32), and zero d_out ----
__global__ __launch_bounds__(128) void sdd4_prep(
    const float* __restrict__ Mmat,    // [32,32]
    const float* __restrict__ Bbasis,  // [81,32]
    float* __restrict__ G,             // [81,32] (d_ws)
    float* __restrict__ out)           // [4,32]
{
    __shared__ float M_lds[32 * 33];   // [n][m] padded
    const int t  = threadIdx.x;
    const int bx = blockIdx.x;         // 0..3

    const float4* M4 = reinterpret_cast<const float4*>(Mmat);
    for (int i = t; i < 256; i += 128) {
        float4 v = M4[i];
        float* dst = &M_lds[(i >> 3) * 33 + (i & 7) * 4];
        dst[0] = v.x; dst[1] = v.y; dst[2] = v.z; dst[3] = v.w;
    }
    if (bx == 0 && t < 128) out[t] = 0.0f;
    __syncthreads();

    const int base = bx * 648;         // 2592 / 4
    for (int k = 0; k < 6; ++k) {
        const int o = base + t + k * 128;
        if (o < base + 648) {
            const int jf = o >> 5, m = o & 31;
            const float4* Br = reinterpret_cast<const float4*>(Bbasis + jf * 32);
            float acc = 0.f;
            #pragma unroll
            for (int nv = 0; nv < 8; ++nv) {
                float4 bv = Br[nv];
                acc = fmaf(bv.x, M_lds[(nv * 4 + 0) * 33 + m], acc);
                acc = fmaf(bv.y, M_lds[(nv * 4 + 1) * 33 + m], acc);
                acc = fmaf(bv.z, M_lds[(nv * 4 + 2) * 33 + m], acc);
                acc = fmaf(bv.w, M_lds[(nv * 4 + 3) * 33 + m], acc);
            }
            G[o] = acc;
        }
    }
}

// ---- main: one block per (b,p,q), 256 threads; HBM pass + tiny epilogue ----
__global__ __launch_bounds__(256) void sdd4_main(
    const float* __restrict__ arr,     // [4,16,16,16,16,32]
    const float* __restrict__ G,       // [81,32]
    const float* __restrict__ Acoeff,  // [32,81]
    float* __restrict__ out)           // [4,32]
{
    __shared__ float4 U_lds[800];      // [(r*2+h)*25 + c*8 + mv]  (24->25 pad)
    __shared__ float  V_lds[9 * 33];   // [jj][m]
    __shared__ float  G_lds[81 * 33];  // [jf][m]
    __shared__ __align__(16) float A_lds[32 * 81];  // Acoeff row-major (81 odd: conflict-free)
    __shared__ float  c_lds[40];
    __shared__ int    jf_lds[40];

    const int t  = threadIdx.x;
    const int bx = blockIdx.x;         // 0..1023
    const int b  = bx >> 8;
    const int p  = (bx >> 4) & 15;
    const int q  = bx & 15;

    const int mv = t & 7;              // float4 idx within m
    const int h  = (t >> 3) & 1;       // s-half
    const int r  = t >> 4;             // 0..15

    // ---- issue the HBM pass loads FIRST (latency overlapped with staging) ----
    const float4* A4 = reinterpret_cast<const float4*>(arr);
    const size_t tile = (size_t)((b * 16 + p) * 16 + q) * 2048;
    float4 x[8];
    #pragma unroll
    for (int i = 0; i < 8; ++i)
        x[i] = A4[tile + (size_t)((r * 16 + h * 8 + i) * 8 + mv)];

    // ---- stage G (padded) and Acoeff (flat, coalesced float4) ----
    const float4* G4 = reinterpret_cast<const float4*>(G);
    for (int i = t; i < 648; i += 256) {
        float4 v = G4[i];
        float* dst = &G_lds[(i >> 3) * 33 + (i & 7) * 4];
        dst[0] = v.x; dst[1] = v.y; dst[2] = v.z; dst[3] = v.w;
    }
    const float4* Ac4 = reinterpret_cast<const float4*>(Acoeff);
    float4* Al4 = reinterpret_cast<float4*>(A_lds);
    for (int i = t; i < 648; i += 256)
        Al4[i] = Ac4[i];

    // ---- per-half class partials ----
    float4 u0 = make_float4(0.f, 0.f, 0.f, 0.f), u1 = u0, u2 = u0;
    const unsigned m0 = 0x36DBu >> (h * 8);
    const unsigned m1 = 0x6DB6u >> (h * 8);
    const unsigned m2 = 0xDB6Cu >> (h * 8);
    #pragma unroll
    for (int i = 0; i < 8; ++i) {
        if ((m0 >> i) & 1) add4(u0, x[i]);
        if ((m1 >> i) & 1) add4(u1, x[i]);
        if ((m2 >> i) & 1) add4(u2, x[i]);
    }
    const int ub = (r * 2 + h) * 25;
    U_lds[ub +      mv] = u0;
    U_lds[ub +  8 + mv] = u1;
    U_lds[ub + 16 + mv] = u2;
    __syncthreads();

    // ---- reduce over (r,h) per class -> V[jj][m], jj = j3*3 + j4 ----
    if (t < 72) {
        const int j3  = t / 24;
        const int rem = t % 24;
        const int j4  = rem >> 3;
        const int mv2 = rem & 7;
        const unsigned msk = (j3 == 0) ? 0x36DBu : (j3 == 1 ? 0x6DB6u : 0xDB6Cu);
        float4 acc = make_float4(0.f, 0.f, 0.f, 0.f);
        #pragma unroll
        for (int rr = 0; rr < 16; ++rr) {
            if ((msk >> rr) & 1) {
                add4(acc, U_lds[(rr * 2 + 0) * 25 + j4 * 8 + mv2]);
                add4(acc, U_lds[(rr * 2 + 1) * 25 + j4 * 8 + mv2]);
            }
        }
        const int jj = j3 * 3 + j4;
        float* dv = &V_lds[jj * 33 + mv2 * 4];
        dv[0] = acc.x; dv[1] = acc.y; dv[2] = acc.z; dv[3] = acc.w;
    }
    __syncthreads();

    // ---- combos for this (p,q): c_jf = G[jf,:] . V[jj,:] ----
    int l1_0, l1_1 = 0, n1;
    if      (p == 0)  { l1_0 = 0; n1 = 1; }
    else if (p == 15) { l1_0 = 2; n1 = 1; }
    else              { l1_0 = (p - 1) % 3; l1_1 = p % 3; n1 = 2; }
    int l2_0, l2_1 = 0, n2;
    if      (q == 0)  { l2_0 = 0; n2 = 1; }
    else if (q == 15) { l2_0 = 2; n2 = 1; }
    else              { l2_0 = (q - 1) % 3; l2_1 = q % 3; n2 = 2; }

    const int ncomb = n1 * n2 * 9;
    if (t < ncomb) {
        const int jj  = t % 9;
        const int c12 = t / 9;
        const int i1idx = (n2 == 2) ? (c12 >> 1) : c12;
        const int i2idx = (n2 == 2) ? (c12 & 1)  : 0;
        const int i1 = i1idx ? l1_1 : l1_0;
        const int i2 = i2idx ? l2_1 : l2_0;
        const int jf = (i1 * 3 + i2) * 9 + jj;
        float acc = 0.f;
        #pragma unroll
        for (int m = 0; m < 32; ++m)
            acc = fmaf(G_lds[jf * 33 + m], V_lds[jj * 33 + m], acc);
        c_lds[t]  = acc;
        jf_lds[t] = jf;
    }
    __syncthreads();

    // ---- apply Acoeff, one atomic per (b,n) per block ----
    if (t < 32) {
        float acc = 0.f;
        for (int k = 0; k < ncomb; ++k)
            acc = fmaf(A_lds[t * 81 + jf_lds[k]], c_lds[k], acc);
        atomicAdd(&out[b * 32 + t], acc * (1.0f / 810000.0f));
    }
}

extern "C" void kernel_launch(void* const* d_in, const int* in_sizes, int n_in,
                              void* d_out, int out_size, void* d_ws, size_t ws_size,
                              hipStream_t stream) {
    const float* arr    = (const float*)d_in[0];  // [4,16,16,16,16,32]
    const float* Mmat   = (const float*)d_in[1];  // [32,32]
    const float* Acoeff = (const float*)d_in[2];  // [32,81]
    const float* Bbasis = (const float*)d_in[3];  // [81,32]
    float* G = (float*)d_ws;                      // 81*32 floats

    sdd4_prep<<<dim3(4),    dim3(128), 0, stream>>>(Mmat, Bbasis, G, (float*)d_out);
    sdd4_main<<<dim3(1024), dim3(256), 0, stream>>>(arr, G, Acoeff, (float*)d_out);
}